// Round 4
// baseline (1308.564 us; speedup 1.0000x reference)
//
#include <hip/hip_runtime.h>
#include <hip/hip_bf16.h>

// HunyuanTopKGate: x[4096,4096] fp32, wg[64,4096] fp32 ->
//   combine_weights [T,E,C] fp32 ++ dispatch_mask [T,E,C] (as fp32 0/1)
// C = out_size/(2*T*E) = 2268 -> 4.76 GB output zero-fill (~760us at the
// 6.2 TB/s fill ceiling) is the roofline pole.
//
// Round 14: R13 falsified "ws is PCIe" (moving partial to HBM changed
// nothing). absmax bit-identical R10-R13 -> repair never ran. Structure
// is ~760 fill + ~490 invisible tail in every round. This round: retry
// the block-specialized overlap (fill || gemm in one dispatch -- the only
// legal overlap on one serial stream) with R12's two suspected killers
// fixed: (1) NT stores -> PLAIN unrolled dwordx4 (NT likely bypassed L2
// write-combining -> ~4TB/s; rocclr's 6.24TB/s fill is plain), (2) drop
// __launch_bounds__ min-blocks=3 (VGPR clamp -> probable scratch spills
// in the gemm branch). mega has a unique name and is the largest
// dispatch -> its counters MUST show in top-5 -> direct fill-BW + tail
// decomposition next round. verify -> gated fp64 repair unchanged.
//
// ws: partial[8][4096][64] f64 | idx_kt | w_kt | flag | wp[3][64][4096] bf16

#define TOK 4096
#define HID 4096
#define NE  64
#define NK  8

typedef __attribute__((ext_vector_type(8))) short short8;   // 8 bf16
typedef __attribute__((ext_vector_type(4))) float f32x4;

__device__ __forceinline__ short f2bf(float f) {
  __hip_bfloat16 h = __float2bfloat16(f);   // RNE
  return *reinterpret_cast<short*>(&h);
}
__device__ __forceinline__ float bf2f(short s) {
  unsigned u = ((unsigned)(unsigned short)s) << 16;
  return __uint_as_float(u);
}
__device__ __forceinline__ void cvt3(float f, short& s0, short& s1, short& s2) {
  s0 = f2bf(f);
  float r1 = f - bf2f(s0);
  s1 = f2bf(r1);
  float r2 = r1 - bf2f(s1);
  s2 = f2bf(r2);
}

// ---------------- 0. prep: wg fp32 -> 3 bf16 planes in ws (R12-proven) ----
__global__ __launch_bounds__(256) void prep_wg(
    const float* __restrict__ wg, short* __restrict__ wp) {
  const int idx = blockIdx.x * 256 + threadIdx.x;   // 0..65535
  const int e  = idx >> 10;                         // row (1024 f4/row)
  const int kq = idx & 1023;
  float4 v = *(const float4*)&wg[(size_t)e * HID + kq * 4];
  short4 p0, p1, p2;
  cvt3(v.x, p0.x, p1.x, p2.x);  cvt3(v.y, p0.y, p1.y, p2.y);
  cvt3(v.z, p0.z, p1.z, p2.z);  cvt3(v.w, p0.w, p1.w, p2.w);
  *(short4*)&wp[((size_t)  0 + e) * HID + kq * 4] = p0;
  *(short4*)&wp[((size_t) 64 + e) * HID + kq * 4] = p1;
  *(short4*)&wp[((size_t)128 + e) * HID + kq * 4] = p2;
}

// ---------------- 1. mega: gemm blocks (bx<ngemm) + plain-fill blocks -----
// gemm branch: R12-proven correct (absmax matched): A staged in LDS
// (27.6KB, stride 72 shorts = 16B-aligned b128 frags, 2-way banks free);
// B-frags direct from wp (1.5MB, L2-resident). NO min-blocks hint: let
// VGPR float (R12's ,3 hint likely forced spills).
// fill branch: plain (non-NT) dwordx4 stores, 4x unrolled, coalesced.
__global__ __launch_bounds__(256) void mega(
    const float* __restrict__ x, const short* __restrict__ wp,
    double* __restrict__ partial, int kchunk, int ngemm, int nfill,
    int* __restrict__ flag, float* __restrict__ out, int out_n) {
  const int bx  = blockIdx.x;
  const int tid = threadIdx.x;

  if (bx >= ngemm) {                    // ---- fill branch ----
    const int    fid    = bx - ngemm;
    const size_t n4     = ((size_t)(unsigned)out_n) >> 2;
    const size_t stride = (size_t)nfill * 256;
    f32x4* o4 = (f32x4*)out;
    const f32x4 z4 = (f32x4){0.f, 0.f, 0.f, 0.f};
    size_t i = (size_t)fid * 256 + tid;
    for (; i + 3 * stride < n4; i += 4 * stride) {
      o4[i]              = z4;
      o4[i + stride]     = z4;
      o4[i + 2 * stride] = z4;
      o4[i + 3 * stride] = z4;
    }
    for (; i < n4; i += stride) o4[i] = z4;
    if (fid == 0 && tid == 0)           // out_n % 4 == 0 -> empty, kept safe
      for (size_t i2 = n4 << 2; i2 < (size_t)(unsigned)out_n; ++i2) out[i2] = 0.f;
    return;
  }

  // ---- gemm branch ----
  __shared__ __align__(16) short XA[3][64][72];   // 27.6 KB
  if (bx == 0 && tid == 0) *flag = 0;
  const int tileid = bx & 63;
  const int slab   = bx >> 6;
  const int t0   = tileid * 64;
  const int k0   = slab * kchunk;
  const int lane = tid & 63;
  const int w    = tid >> 6;
  const int m    = lane & 15;       // frag row/col within 16
  const int q    = lane >> 4;       // quad
  const int lrow = tid >> 2;        // staging: 4 threads per row
  const int lq   = tid & 3;         // 16 floats each

  f32x4 acc[4];
#pragma unroll
  for (int nt = 0; nt < 4; ++nt) acc[nt] = (f32x4){0.f, 0.f, 0.f, 0.f};

  for (int s = 0; s < kchunk; s += 64) {
    const int kk = k0 + s;
#pragma unroll
    for (int c = 0; c < 4; ++c) {
      const int col = lq * 16 + c * 4;
      float4 xv = *(const float4*)&x[(size_t)(t0 + lrow) * HID + kk + col];
      short4 p0, p1, p2;
      cvt3(xv.x, p0.x, p1.x, p2.x);  cvt3(xv.y, p0.y, p1.y, p2.y);
      cvt3(xv.z, p0.z, p1.z, p2.z);  cvt3(xv.w, p0.w, p1.w, p2.w);
      *(short4*)&XA[0][lrow][col] = p0;
      *(short4*)&XA[1][lrow][col] = p1;
      *(short4*)&XA[2][lrow][col] = p2;
    }
    __syncthreads();
#pragma unroll
    for (int kc = 0; kc < 64; kc += 32) {
      short8 a0 = *(const short8*)&XA[0][w * 16 + m][kc + q * 8];
      short8 a1 = *(const short8*)&XA[1][w * 16 + m][kc + q * 8];
      short8 a2 = *(const short8*)&XA[2][w * 16 + m][kc + q * 8];
#pragma unroll
      for (int nt = 0; nt < 4; ++nt) {
        const size_t roff = (size_t)(nt * 16 + m) * HID + (kk + kc + q * 8);
        short8 b0 = *(const short8*)&wp[roff];                       // plane 0
        short8 b1 = *(const short8*)&wp[(size_t) 64 * HID + roff];   // plane 1
        short8 b2 = *(const short8*)&wp[(size_t)128 * HID + roff];   // plane 2
        acc[nt] = __builtin_amdgcn_mfma_f32_16x16x32_bf16(a0, b0, acc[nt], 0, 0, 0);
        acc[nt] = __builtin_amdgcn_mfma_f32_16x16x32_bf16(a0, b1, acc[nt], 0, 0, 0);
        acc[nt] = __builtin_amdgcn_mfma_f32_16x16x32_bf16(a1, b0, acc[nt], 0, 0, 0);
        acc[nt] = __builtin_amdgcn_mfma_f32_16x16x32_bf16(a0, b2, acc[nt], 0, 0, 0);
        acc[nt] = __builtin_amdgcn_mfma_f32_16x16x32_bf16(a1, b1, acc[nt], 0, 0, 0);
        acc[nt] = __builtin_amdgcn_mfma_f32_16x16x32_bf16(a2, b0, acc[nt], 0, 0, 0);
      }
    }
    __syncthreads();
  }

  // C/D: row = q*4 + v (token), col = m (expert within n-tile)  [m89/m91]
  double* base = partial + (size_t)slab * TOK * NE;
#pragma unroll
  for (int nt = 0; nt < 4; ++nt)
#pragma unroll
    for (int v = 0; v < 4; ++v)
      base[(size_t)(t0 + w * 16 + q * 4 + v) * NE + nt * 16 + m] =
          (double)acc[nt][v];
}

// ---------------- 1b. verify: sample 512 logits vs exact fp64 dots --------
__global__ __launch_bounds__(256) void verify_kernel(
    const float* __restrict__ x, const float* __restrict__ wg,
    const double* __restrict__ partial, int nsplit, int* __restrict__ flag) {
  const int gid  = blockIdx.x * blockDim.x + threadIdx.x;
  const int wid  = gid >> 6;          // 0..511
  const int lane = gid & 63;
  const int t = (wid * 521) & (TOK - 1);
  const int e = wid & 63;
  double acc = 0.0;
  for (int k = lane; k < HID; k += 64)
    acc = fma((double)x[(size_t)t * HID + k], (double)wg[(size_t)e * HID + k], acc);
#pragma unroll
  for (int off = 32; off; off >>= 1) acc += __shfl_xor(acc, off);
  if (lane == 0) {
    double got = 0.0;
    for (int p = 0; p < nsplit; ++p)
      got += partial[(size_t)p * TOK * NE + (size_t)t * NE + e];
    if (!(fabs(got - acc) <= 1e-3)) atomicOr(flag, 1);  // NaN-safe
  }
}

// ---------------- 1c. repair: R9's proven fp64 split-K gemm, flag-gated ---
__global__ __launch_bounds__(256) void repair_splitk(
    const float* __restrict__ x, const float* __restrict__ wg,
    double* __restrict__ partial, int kchunk, const int* __restrict__ flag) {
  if (*(volatile const int*)flag == 0) return;
  __shared__ float xs[16][68];
  __shared__ float wsh[64][68];
  const int tid = threadIdx.x;
  const int t0  = blockIdx.x * 16;
  const int k0  = blockIdx.y * kchunk;
  const int tok = tid & 15;
  const int eg  = tid >> 4;
  const int lrow = tid >> 4;
  const int lq   = tid & 15;
  double acc[4] = {0.0, 0.0, 0.0, 0.0};

  for (int s = 0; s < kchunk; s += 64) {
    const int kk = k0 + s;
    {
      float4 v = *(const float4*)&x[(size_t)(t0 + lrow) * HID + kk + lq * 4];
      *(float4*)&xs[lrow][lq * 4] = v;
    }
#pragma unroll
    for (int it = 0; it < 4; ++it) {
      int r = it * 16 + lrow;
      float4 v = *(const float4*)&wg[(size_t)r * HID + kk + lq * 4];
      *(float4*)&wsh[r][lq * 4] = v;
    }
    __syncthreads();
#pragma unroll
    for (int kc = 0; kc < 64; kc += 4) {
      float4 xv = *(const float4*)&xs[tok][kc];
#pragma unroll
      for (int j = 0; j < 4; ++j) {
        float4 wv = *(const float4*)&wsh[eg * 4 + j][kc];
        acc[j] = fma((double)xv.x, (double)wv.x, acc[j]);
        acc[j] = fma((double)xv.y, (double)wv.y, acc[j]);
        acc[j] = fma((double)xv.z, (double)wv.z, acc[j]);
        acc[j] = fma((double)xv.w, (double)wv.w, acc[j]);
      }
    }
    __syncthreads();
  }
  double* base = partial + (size_t)blockIdx.y * TOK * NE;
#pragma unroll
  for (int j = 0; j < 4; ++j)
    base[(size_t)(t0 + tok) * NE + eg * 4 + j] = acc[j];
}

// ---------------- 2. softmax + top-8 per token (one wave64/token) ----------
__global__ __launch_bounds__(256) void topk_kernel(
    const double* __restrict__ partial, int nsplit,
    int* __restrict__ idx_kt, float* __restrict__ w_kt) {
  const int gid  = blockIdx.x * blockDim.x + threadIdx.x;
  const int t    = gid >> 6;
  const int lane = gid & 63;

  double v = 0.0;
  for (int p = 0; p < nsplit; ++p)
    v += partial[(size_t)p * TOK * NE + (size_t)t * NE + lane];

  double m = v;
#pragma unroll
  for (int off = 32; off; off >>= 1) {
    double o = __shfl_xor(m, off);
    m = o > m ? o : m;
  }
  double g = exp(v - m);
  double s = g;
#pragma unroll
  for (int off = 32; off; off >>= 1) s += __shfl_xor(s, off);
  double gate = g / s;

  float key = (float)gate;    // fp32-rounded key, tie -> lower index
  double ssel = 0.0;
  int my_k = -1;
#pragma unroll
  for (int k = 0; k < NK; ++k) {
    float bv = key;
    int   bi = lane;
#pragma unroll
    for (int off = 32; off; off >>= 1) {
      float ov = __shfl_xor(bv, off);
      int   oi = __shfl_xor(bi, off);
      if (ov > bv || (ov == bv && oi < bi)) { bv = ov; bi = oi; }
    }
    ssel += __shfl(gate, bi);
    if (lane == bi) { my_k = k; key = -1.0f; }
  }
  double gs = ssel;
  const double eps = (double)1.1920929e-07f;
  if (gs < eps) gs = eps;

  if (my_k >= 0) {
    idx_kt[my_k * TOK + t] = lane;
    w_kt [my_k * TOK + t] = (float)(gate / gs);
  }
}

// ---------------- 3. fused rank + scatter ------------------------------
__global__ __launch_bounds__(1024) void rank_scatter(
    const int* __restrict__ idx_kt, const float* __restrict__ w_kt,
    float* __restrict__ out, int C) {
  const int e    = blockIdx.x;
  const int tid  = threadIdx.x;
  const int lane = tid & 63;
  const int w    = tid >> 6;          // 0..15
  __shared__ int wt[16];
  int running = 0;
  const unsigned long long below = (1ull << lane) - 1ull;

  for (int i0 = 0; i0 < NK * TOK; i0 += 1024) {
    const int i = i0 + tid;
    const bool mhit = (idx_kt[i] == e);
    unsigned long long mask = __ballot(mhit);
    if (lane == 0) wt[w] = __popcll(mask);
    __syncthreads();
    int woff = 0, tot = 0;
#pragma unroll
    for (int j = 0; j < 16; ++j) {
      int c = wt[j];
      tot += c;
      if (j < w) woff += c;
    }
    if (mhit) {
      const int c = running + woff + __popcll(mask & below);
      if (c < C) {
        const int t = i & (TOK - 1);
        size_t off = ((size_t)t * NE + e) * (size_t)C + (size_t)c;
        out[off] = w_kt[i];                          // combine_weights
        out[(size_t)TOK * NE * C + off] = 1.0f;      // dispatch_mask
      }
    }
    running += tot;
    __syncthreads();
  }
}

extern "C" void kernel_launch(void* const* d_in, const int* in_sizes, int n_in,
                              void* d_out, int out_size, void* d_ws, size_t ws_size,
                              hipStream_t stream) {
  const float* x  = (const float*)d_in[0];   // [4096,4096]
  const float* wg = (const float*)d_in[1];   // [64,4096]
  float* out = (float*)d_out;

  const int C = out_size / (2 * TOK * NE);   // capacity from output size

  const size_t slab = (size_t)TOK * NE * sizeof(double);   // 2 MB per partial
  const size_t tail = 2 * (size_t)NK * TOK * sizeof(int);  // idx + w
  const size_t wpb  = (size_t)3 * NE * HID * sizeof(short);// 1.5 MB bf16 planes
  int nsplit = 8;
  while (nsplit > 1 && (size_t)nsplit * slab + tail + 64 + wpb > ws_size) nsplit >>= 1;
  const int kchunk = HID / nsplit;

  char* ws = (char*)d_ws;
  double* partial = (double*)ws;
  int*    idx_kt  = (int*)  (ws + (size_t)nsplit * slab);
  float*  w_kt    = (float*)(ws + (size_t)nsplit * slab + (size_t)NK * TOK * 4);
  int*    flag    = (int*)  (ws + (size_t)nsplit * slab + tail);
  short*  wp      = (short*)(ws + (size_t)nsplit * slab + tail + 64);

  const int ngemm = 64 * nsplit;    // 512 gemm blocks at nsplit=8
  const int nfill = 2048;           // plain-store fill blocks

  prep_wg      <<<256, 256, 0, stream>>>(wg, wp);
  mega         <<<ngemm + nfill, 256, 0, stream>>>(x, wp, partial, kchunk,
                                                   ngemm, nfill, flag, out, out_size);
  verify_kernel<<<128, 256, 0, stream>>>(x, wg, partial, nsplit, flag);
  dim3 rgrid(TOK / 16, nsplit);
  repair_splitk<<<rgrid, 256, 0, stream>>>(x, wg, partial, kchunk, flag);
  topk_kernel  <<<TOK * 64 / 256, 256, 0, stream>>>(partial, nsplit, idx_kt, w_kt);
  rank_scatter <<<NE, 1024, 0, stream>>>(idx_kt, w_kt, out, C);
}

// Round 5
// 1269.899 us; speedup vs baseline: 1.0304x; 1.0304x over previous
//
#include <hip/hip_runtime.h>
#include <hip/hip_bf16.h>

// HunyuanTopKGate: x[4096,4096] fp32, wg[64,4096] fp32 ->
//   combine_weights [T,E,C] fp32 ++ dispatch_mask [T,E,C] (as fp32 0/1)
// C = out_size/(2*T*E) = 2268 -> 4.76 GB output zero-fill (~760us at the
// 6.2 TB/s fill ceiling) is the roofline pole.
//
// Round 15: decomposition finally closed. mega absent from top-5 in
// R11/R12/R14 -> the fused fill+gemm runs at fill-alone speed (<=764us).
// Yet totals stayed ~1250-1310 in ALL rounds regardless of structure ->
// the constant ~480-540us is NOT any kernel body: it fits a fixed
// ~80-90us per-dispatch cost (6 dispatches every round). Test + exploit:
// cut to 3 dispatches: mega (fill + R10-verbatim gemm, in-LDS WB -> no
// prep), topk, rank_scatter. Verify/repair removed: never fired in 5
// rounds (absmax bit-identical, fixed input). No numerics change ->
// absmax must stay 0.0004882812. Predict ~1030-1080 if theory holds;
// if ~1250 persists, sink is inside topk/scatter -> bisect next round.
//
// ws: partial[8][4096][64] f64 (16MB) | idx_kt | w_kt

#define TOK 4096
#define HID 4096
#define NE  64
#define NK  8
#define NSPLIT 8

typedef __attribute__((ext_vector_type(8))) short short8;   // 8 bf16
typedef __attribute__((ext_vector_type(4))) float f32x4;

__device__ __forceinline__ short f2bf(float f) {
  __hip_bfloat16 h = __float2bfloat16(f);   // RNE
  return *reinterpret_cast<short*>(&h);
}
__device__ __forceinline__ float bf2f(short s) {
  unsigned u = ((unsigned)(unsigned short)s) << 16;
  return __uint_as_float(u);
}
__device__ __forceinline__ void cvt3(float f, short& s0, short& s1, short& s2) {
  s0 = f2bf(f);
  float r1 = f - bf2f(s0);
  s1 = f2bf(r1);
  float r2 = r1 - bf2f(s1);
  s2 = f2bf(r2);
}

// ---------------- 1. mega: R10 gemm blocks + plain-store fill blocks ------
// gemm blocks (bx < 512): tile = bx&63 (64 tokens), slab = bx>>6.
// R10-verbatim body (absmax-verified 5 rounds): XA+WB bf16x3 planes in
// LDS (55.3KB, stride 72 shorts = 16B-aligned b128 frags, 2-way banks
// free), 6 cross-term MFMAs into one fp32 acc.
// fill blocks (bx >= 512): plain dwordx4 grid-stride stores, 4x unrolled
// (R14-proven: mega <= 764us). 55.3KB LDS caps residency at 2 blocks/CU;
// fill starts after gemm blocks retire (~40us) -- acceptable.
__global__ __launch_bounds__(256) void mega(
    const float* __restrict__ x, const float* __restrict__ wg,
    double* __restrict__ partial, int kchunk, int ngemm, int nfill,
    float* __restrict__ out, int out_n) {
  const int bx  = blockIdx.x;
  const int tid = threadIdx.x;

  if (bx >= ngemm) {                    // ---- fill branch ----
    const int    fid    = bx - ngemm;
    const size_t n4     = ((size_t)(unsigned)out_n) >> 2;
    const size_t stride = (size_t)nfill * 256;
    f32x4* o4 = (f32x4*)out;
    const f32x4 z4 = (f32x4){0.f, 0.f, 0.f, 0.f};
    size_t i = (size_t)fid * 256 + tid;
    for (; i + 3 * stride < n4; i += 4 * stride) {
      o4[i]              = z4;
      o4[i + stride]     = z4;
      o4[i + 2 * stride] = z4;
      o4[i + 3 * stride] = z4;
    }
    for (; i < n4; i += stride) o4[i] = z4;
    if (fid == 0 && tid == 0)           // out_n % 4 == 0 -> empty, kept safe
      for (size_t i2 = n4 << 2; i2 < (size_t)(unsigned)out_n; ++i2) out[i2] = 0.f;
    return;
  }

  // ---- gemm branch (R10 verbatim) ----
  __shared__ __align__(16) short XA[3][64][72];   // 27.6 KB
  __shared__ __align__(16) short WB[3][64][72];   // 27.6 KB
  const int tileid = bx & 63;
  const int slab   = bx >> 6;
  const int t0   = tileid * 64;
  const int k0   = slab * kchunk;
  const int lane = tid & 63;
  const int w    = tid >> 6;
  const int m    = lane & 15;       // frag row/col within 16
  const int q    = lane >> 4;       // quad
  const int lrow = tid >> 2;        // staging: 4 threads per row
  const int lq   = tid & 3;         // 16 floats each

  f32x4 acc[4];
#pragma unroll
  for (int nt = 0; nt < 4; ++nt) acc[nt] = (f32x4){0.f, 0.f, 0.f, 0.f};

  for (int s = 0; s < kchunk; s += 64) {
    const int kk = k0 + s;
#pragma unroll
    for (int c = 0; c < 4; ++c) {
      const int col = lq * 16 + c * 4;
      float4 xv = *(const float4*)&x [(size_t)(t0 + lrow) * HID + kk + col];
      float4 wv = *(const float4*)&wg[(size_t)lrow * HID + kk + col];
      short4 p0, p1, p2;
      cvt3(xv.x, p0.x, p1.x, p2.x);  cvt3(xv.y, p0.y, p1.y, p2.y);
      cvt3(xv.z, p0.z, p1.z, p2.z);  cvt3(xv.w, p0.w, p1.w, p2.w);
      *(short4*)&XA[0][lrow][col] = p0;
      *(short4*)&XA[1][lrow][col] = p1;
      *(short4*)&XA[2][lrow][col] = p2;
      cvt3(wv.x, p0.x, p1.x, p2.x);  cvt3(wv.y, p0.y, p1.y, p2.y);
      cvt3(wv.z, p0.z, p1.z, p2.z);  cvt3(wv.w, p0.w, p1.w, p2.w);
      *(short4*)&WB[0][lrow][col] = p0;
      *(short4*)&WB[1][lrow][col] = p1;
      *(short4*)&WB[2][lrow][col] = p2;
    }
    __syncthreads();
#pragma unroll
    for (int kc = 0; kc < 64; kc += 32) {
      short8 a0 = *(const short8*)&XA[0][w * 16 + m][kc + q * 8];
      short8 a1 = *(const short8*)&XA[1][w * 16 + m][kc + q * 8];
      short8 a2 = *(const short8*)&XA[2][w * 16 + m][kc + q * 8];
#pragma unroll
      for (int nt = 0; nt < 4; ++nt) {
        short8 b0 = *(const short8*)&WB[0][nt * 16 + m][kc + q * 8];
        short8 b1 = *(const short8*)&WB[1][nt * 16 + m][kc + q * 8];
        short8 b2 = *(const short8*)&WB[2][nt * 16 + m][kc + q * 8];
        acc[nt] = __builtin_amdgcn_mfma_f32_16x16x32_bf16(a0, b0, acc[nt], 0, 0, 0);
        acc[nt] = __builtin_amdgcn_mfma_f32_16x16x32_bf16(a0, b1, acc[nt], 0, 0, 0);
        acc[nt] = __builtin_amdgcn_mfma_f32_16x16x32_bf16(a1, b0, acc[nt], 0, 0, 0);
        acc[nt] = __builtin_amdgcn_mfma_f32_16x16x32_bf16(a0, b2, acc[nt], 0, 0, 0);
        acc[nt] = __builtin_amdgcn_mfma_f32_16x16x32_bf16(a1, b1, acc[nt], 0, 0, 0);
        acc[nt] = __builtin_amdgcn_mfma_f32_16x16x32_bf16(a2, b0, acc[nt], 0, 0, 0);
      }
    }
    __syncthreads();
  }

  // C/D: row = q*4 + v (token), col = m (expert within n-tile)  [m89/m91]
  double* base = partial + (size_t)slab * TOK * NE;
#pragma unroll
  for (int nt = 0; nt < 4; ++nt)
#pragma unroll
    for (int v = 0; v < 4; ++v)
      base[(size_t)(t0 + w * 16 + q * 4 + v) * NE + nt * 16 + m] =
          (double)acc[nt][v];
}

// ---------------- 2. softmax + top-8 per token (one wave64/token) ----------
__global__ __launch_bounds__(256) void topk_kernel(
    const double* __restrict__ partial, int nsplit,
    int* __restrict__ idx_kt, float* __restrict__ w_kt) {
  const int gid  = blockIdx.x * blockDim.x + threadIdx.x;
  const int t    = gid >> 6;
  const int lane = gid & 63;

  double v = 0.0;
  for (int p = 0; p < nsplit; ++p)
    v += partial[(size_t)p * TOK * NE + (size_t)t * NE + lane];

  double m = v;
#pragma unroll
  for (int off = 32; off; off >>= 1) {
    double o = __shfl_xor(m, off);
    m = o > m ? o : m;
  }
  double g = exp(v - m);
  double s = g;
#pragma unroll
  for (int off = 32; off; off >>= 1) s += __shfl_xor(s, off);
  double gate = g / s;

  float key = (float)gate;    // fp32-rounded key, tie -> lower index
  double ssel = 0.0;
  int my_k = -1;
#pragma unroll
  for (int k = 0; k < NK; ++k) {
    float bv = key;
    int   bi = lane;
#pragma unroll
    for (int off = 32; off; off >>= 1) {
      float ov = __shfl_xor(bv, off);
      int   oi = __shfl_xor(bi, off);
      if (ov > bv || (ov == bv && oi < bi)) { bv = ov; bi = oi; }
    }
    ssel += __shfl(gate, bi);
    if (lane == bi) { my_k = k; key = -1.0f; }
  }
  double gs = ssel;
  const double eps = (double)1.1920929e-07f;
  if (gs < eps) gs = eps;

  if (my_k >= 0) {
    idx_kt[my_k * TOK + t] = lane;
    w_kt [my_k * TOK + t] = (float)(gate / gs);
  }
}

// ---------------- 3. fused rank + scatter ------------------------------
__global__ __launch_bounds__(1024) void rank_scatter(
    const int* __restrict__ idx_kt, const float* __restrict__ w_kt,
    float* __restrict__ out, int C) {
  const int e    = blockIdx.x;
  const int tid  = threadIdx.x;
  const int lane = tid & 63;
  const int w    = tid >> 6;          // 0..15
  __shared__ int wt[16];
  int running = 0;
  const unsigned long long below = (1ull << lane) - 1ull;

  for (int i0 = 0; i0 < NK * TOK; i0 += 1024) {
    const int i = i0 + tid;
    const bool mhit = (idx_kt[i] == e);
    unsigned long long mask = __ballot(mhit);
    if (lane == 0) wt[w] = __popcll(mask);
    __syncthreads();
    int woff = 0, tot = 0;
#pragma unroll
    for (int j = 0; j < 16; ++j) {
      int c = wt[j];
      tot += c;
      if (j < w) woff += c;
    }
    if (mhit) {
      const int c = running + woff + __popcll(mask & below);
      if (c < C) {
        const int t = i & (TOK - 1);
        size_t off = ((size_t)t * NE + e) * (size_t)C + (size_t)c;
        out[off] = w_kt[i];                          // combine_weights
        out[(size_t)TOK * NE * C + off] = 1.0f;      // dispatch_mask
      }
    }
    running += tot;
    __syncthreads();
  }
}

extern "C" void kernel_launch(void* const* d_in, const int* in_sizes, int n_in,
                              void* d_out, int out_size, void* d_ws, size_t ws_size,
                              hipStream_t stream) {
  const float* x  = (const float*)d_in[0];   // [4096,4096]
  const float* wg = (const float*)d_in[1];   // [64,4096]
  float* out = (float*)d_out;

  const int C = out_size / (2 * TOK * NE);   // capacity from output size

  char* ws = (char*)d_ws;
  double* partial = (double*)ws;
  const size_t psz = (size_t)NSPLIT * TOK * NE * sizeof(double);   // 16 MB
  int*    idx_kt  = (int*)  (ws + psz);
  float*  w_kt    = (float*)(ws + psz + (size_t)NK * TOK * sizeof(int));

  const int kchunk = HID / NSPLIT;   // 512
  const int ngemm  = 64 * NSPLIT;    // 512 gemm blocks
  const int nfill  = 2048;           // plain-store fill blocks

  mega        <<<ngemm + nfill, 256, 0, stream>>>(x, wg, partial, kchunk,
                                                  ngemm, nfill, out, out_size);
  topk_kernel <<<TOK * 64 / 256, 256, 0, stream>>>(partial, NSPLIT, idx_kt, w_kt);
  rank_scatter<<<NE, 1024, 0, stream>>>(idx_kt, w_kt, out, C);
}